// Round 5
// baseline (265.387 us; speedup 1.0000x reference)
//
#include <hip/hip_runtime.h>

// SelfMixing: CG tensor-product self-coupling, diagonal in channel.
// Round 5: persistent pipelined blocks. Round-4 post-mortem: occupancy stuck
// at 35% regardless of LDS size; __syncthreads drains vmcnt(0) so every block
// serializes load-latency -> compute -> barrier-drain -> store; ~3.5k stall
// cycles/block exposed. Fixes:
//   - 1024 persistent blocks (4/CU), each loops over 8 consecutive 4-row tiles.
//   - keep/mix coeffs loaded ONCE into registers, reused across tiles.
//   - next-tile inputs PREFETCHED at loop top, consumed next iteration.
//   - barriers via asm "s_waitcnt lgkmcnt(0); s_barrier" (CK block_sync_lds
//     pattern): waits LDS only -> prefetch loads and output stores stay in
//     flight across barriers. No vmcnt(0) drain anywhere in the loop.
// Output repack via LDS (padded rows, 2-way max bank aliasing = free) and
// fully-coalesced float4 stores, as in round 2/4.
// CG tensors compile-time constexpr (Racah + complex->real basis change,
// mirrors reference); zero weights DCE'd.

namespace cgc {

struct cplx { double re, im; };
constexpr cplx cmul(cplx a, cplx b){ return {a.re*b.re - a.im*b.im, a.re*b.im + a.im*b.re}; }

constexpr double cfact(int n){ double r = 1.0; for (int i = 2; i <= n; ++i) r *= i; return r; }
constexpr double cabsd(double x){ return x < 0 ? -x : x; }

constexpr double csqrtd(double x){
  if (x <= 0.0) return 0.0;
  double g = x > 1.0 ? x : 1.0;
  for (int i = 0; i < 48; ++i) g = 0.5*(g + x/g);
  return g;
}

constexpr double SQRT2 = csqrtd(2.0);

constexpr double cg_complex(int l1,int m1,int l2,int m2,int l3,int m3){
  if (m1 + m2 != m3) return 0.0;
  int lo = l1 > l2 ? l1 - l2 : l2 - l1;
  if (l3 < lo || l3 > l1 + l2) return 0.0;
  double pre = csqrtd((2*l3+1) * cfact(l1+l2-l3)*cfact(l1-l2+l3)*cfact(-l1+l2+l3)/cfact(l1+l2+l3+1));
  pre *= csqrtd(cfact(l1+m1)*cfact(l1-m1)*cfact(l2+m2)*cfact(l2-m2)*cfact(l3+m3)*cfact(l3-m3));
  int kmin = 0;
  if (l2-l3-m1 > kmin) kmin = l2-l3-m1;
  if (l1-l3+m2 > kmin) kmin = l1-l3+m2;
  int kmax = l1+l2-l3;
  if (l1-m1 < kmax) kmax = l1-m1;
  if (l2+m2 < kmax) kmax = l2+m2;
  double s = 0.0;
  for (int k = kmin; k <= kmax; ++k){
    double d = cfact(k)*cfact(l1+l2-l3-k)*cfact(l1-m1-k)*cfact(l2+m2-k)
             * cfact(l3-l2+m1+k)*cfact(l3-l1-m2+k);
    s += ((k & 1) ? -1.0 : 1.0) / d;
  }
  return pre * s;
}

// U[r][c]: rows = real m' (r = m'+l), cols = complex m (c = m+l)
constexpr cplx Uent(int l, int r, int c){
  int m = r - l;
  if (m > 0){
    if (c ==  m + l) return { ((m & 1) ? -1.0 : 1.0)/SQRT2, 0.0 };
    if (c == -m + l) return { 1.0/SQRT2, 0.0 };
    return {0.0, 0.0};
  } else if (m == 0){
    if (c == l) return {1.0, 0.0};
    return {0.0, 0.0};
  } else {
    int ma = -m;
    if (c ==  m + l) return { 0.0, 1.0/SQRT2 };
    if (c == -m + l) return { 0.0, -(((ma & 1) ? -1.0 : 1.0))/SQRT2 };
    return {0.0, 0.0};
  }
}

template<int L1,int L2,int L3>
struct CGData { float w[(2*L1+1)*(2*L2+1)*(2*L3+1)]; };

template<int L1,int L2,int L3>
constexpr CGData<L1,L2,L3> make_cg(){
  constexpr int D1 = 2*L1+1, D2 = 2*L2+1, D3 = 2*L3+1;
  cplx U1[D1*D1] = {}; cplx U2[D2*D2] = {}; cplx U3c[D3*D3] = {};
  for (int r = 0; r < D1; ++r) for (int c = 0; c < D1; ++c) U1[r*D1+c] = Uent(L1, r, c);
  for (int r = 0; r < D2; ++r) for (int c = 0; c < D2; ++c) U2[r*D2+c] = Uent(L2, r, c);
  for (int r = 0; r < D3; ++r) for (int c = 0; c < D3; ++c){
    cplx u = Uent(L3, r, c); u.im = -u.im; U3c[r*D3+c] = u;
  }
  double Cc[D1*D2*D3] = {};
  for (int m1 = -L1; m1 <= L1; ++m1)
    for (int m2 = -L2; m2 <= L2; ++m2){
      int m3 = m1 + m2;
      if (m3 < -L3 || m3 > L3) continue;
      Cc[((m1+L1)*D2 + (m2+L2))*D3 + (m3+L3)] = cg_complex(L1,m1,L2,m2,L3,m3);
    }
  double re[D1*D2*D3] = {}; double im[D1*D2*D3] = {};
  for (int a = 0; a < D1; ++a)
    for (int b = 0; b < D2; ++b)
      for (int c = 0; c < D3; ++c){
        double sre = 0.0, sim = 0.0;
        for (int m = 0; m < D1; ++m)
          for (int n = 0; n < D2; ++n){
            int o = m + n - L1 - L2 + L3;
            if (o < 0 || o >= D3) continue;
            double cc = Cc[(m*D2+n)*D3 + o];
            if (cc == 0.0) continue;
            cplx p = cmul(cmul(U1[a*D1+m], U2[b*D2+n]), U3c[c*D3+o]);
            sre += p.re * cc; sim += p.im * cc;
          }
        re[(a*D2+b)*D3+c] = sre; im[(a*D2+b)*D3+c] = sim;
      }
  double mre = 0.0, mim = 0.0;
  for (int k = 0; k < D1*D2*D3; ++k){
    if (cabsd(re[k]) > mre) mre = cabsd(re[k]);
    if (cabsd(im[k]) > mim) mim = cabsd(im[k]);
  }
  CGData<L1,L2,L3> outv{};
  for (int k = 0; k < D1*D2*D3; ++k){
    double v = (mim > mre) ? im[k] : re[k];
    outv.w[k] = (cabsd(v) < 1e-10) ? 0.0f : (float)v;
  }
  return outv;
}

} // namespace cgc

template<int L1,int L2,int L3>
__device__ __forceinline__ void tp_path(const float* xa, const float* xb, float cmix, float* acc){
  constexpr cgc::CGData<L1,L2,L3> cg = cgc::make_cg<L1,L2,L3>();
  constexpr int D1 = 2*L1+1, D2 = 2*L2+1, D3 = 2*L3+1;
  #pragma unroll
  for (int a = 0; a < D1; ++a){
    #pragma unroll
    for (int b = 0; b < D2; ++b){
      const float pr = xa[a] * xb[b];
      #pragma unroll
      for (int m = 0; m < D3; ++m){
        const float W = cg.w[(a*D2+b)*D3 + m];
        if (W != 0.0f) acc[m] += (cmix * W) * pr;   // W is a compile-time constant
      }
    }
  }
}

// LDS-only barrier: waits lgkmcnt(0) then s_barrier. Does NOT drain vmcnt ->
// global prefetch loads and output stores stay in flight (CK block_sync_lds).
__device__ __forceinline__ void sync_lds(){
  asm volatile("s_waitcnt lgkmcnt(0)\n\ts_barrier" ::: "memory");
}

// Layout: OFF_IN = [0,64,208,368]; OFF_OUT = [0,64,208,448,672]
// mix bases: (0,0,0):0 (0,1,1):64 (0,2,2):112 (1,0,1):144 (1,1,0):192 (1,1,1):240
// (1,1,2):288 (1,2,1):336 (1,2,2):368 (1,2,3):400 (2,0,2):432 (2,1,1):464
// (2,1,2):496 (2,1,3):528 (2,2,0):560 (2,2,1):592 (2,2,2):624 (2,2,3):656
// keep bases: l0 -> i, l1 -> 64+i, l2 -> 112+i

constexpr int RPB      = 4;     // rows per tile
constexpr int IN_DIM   = 368;
constexpr int OUT_DIM  = 672;
constexpr int OUT_PAD  = 676;   // +4 floats: float4-aligned; 676%32=4 bank skew/row
constexpr int NBLK     = 1024;  // persistent blocks: 4 per CU

__global__ __launch_bounds__(256, 4) void selfmix_kernel(
    const float* __restrict__ x, const float* __restrict__ keep,
    const float* __restrict__ mix, float* __restrict__ out, int n)
{
  __shared__ float sout[RPB * OUT_PAD];   // 10816 B

  const int tid    = threadIdx.x;
  const int ntiles = (n + RPB - 1) / RPB;
  const int per    = (ntiles + NBLK - 1) / NBLK;
  const int tbeg   = blockIdx.x * per;
  const int tend   = (tbeg + per < ntiles) ? (tbeg + per) : ntiles;
  if (tbeg >= ntiles) return;   // uniform per block; exits before any barrier

  // ---- class geometry (fixed for the whole kernel) ----
  // tid<128: class A, row=tid>>5 (4 rows x 32ch, waves 0-1), i=tid&31
  // tid<192: class B, row=(tid-128)>>4 (4 rows x 16ch, wave 2), i=32+..
  // else   : class C, row=(tid-192)>>4 (4 rows x 16ch, wave 3), i=48+..
  int row, i, cls;
  if (tid < 128){ cls = 0; row = tid >> 5;        i = tid & 31; }
  else if (tid < 192){ cls = 1; row = (tid-128) >> 4; i = 32 + ((tid-128) & 15); }
  else { cls = 2; row = (tid-192) >> 4; i = 48 + ((tid-192) & 15); }

  // ---- persistent coefficients (loaded once) ----
  float cf[21];
  #pragma unroll
  for (int k = 0; k < 21; ++k) cf[k] = 0.f;
  if (cls == 0){
    cf[ 0]=0.5f*mix[    i]; cf[ 1]=0.5f*mix[ 64+i]; cf[ 2]=0.5f*mix[112+i];
    cf[ 3]=0.5f*mix[144+i]; cf[ 4]=0.5f*mix[192+i]; cf[ 5]=0.5f*mix[240+i];
    cf[ 6]=0.5f*mix[288+i]; cf[ 7]=0.5f*mix[336+i]; cf[ 8]=0.5f*mix[368+i];
    cf[ 9]=0.5f*mix[400+i]; cf[10]=0.5f*mix[432+i]; cf[11]=0.5f*mix[464+i];
    cf[12]=0.5f*mix[496+i]; cf[13]=0.5f*mix[528+i]; cf[14]=0.5f*mix[560+i];
    cf[15]=0.5f*mix[592+i]; cf[16]=0.5f*mix[624+i]; cf[17]=0.5f*mix[656+i];
    cf[18]=keep[i]; cf[19]=keep[64+i]; cf[20]=keep[112+i];
  } else if (cls == 1){
    cf[0]=0.5f*mix[    i]; cf[1]=0.5f*mix[ 64+i]; cf[2]=0.5f*mix[144+i];
    cf[3]=0.5f*mix[192+i]; cf[4]=0.5f*mix[240+i]; cf[5]=0.5f*mix[288+i];
    cf[6]=keep[i]; cf[7]=keep[64+i];
  } else {
    cf[0]=0.5f*mix[i]; cf[1]=keep[i];
  }

  // ---- pipelined input registers: cur / next ----
  float cin[9], nin[9];
  #pragma unroll
  for (int k = 0; k < 9; ++k){ cin[k] = 0.f; nin[k] = 0.f; }

  // initial load (tile tbeg)
  {
    const int r0 = tbeg * RPB + row;
    if (r0 < n){
      const float* xr = x + (size_t)r0 * IN_DIM;
      cin[0] = xr[i];
      if (cls <= 1){
        #pragma unroll
        for (int k = 0; k < 3; ++k) cin[1+k] = xr[64 + i*3 + k];
      }
      if (cls == 0){
        #pragma unroll
        for (int k = 0; k < 5; ++k) cin[4+k] = xr[208 + i*5 + k];
      }
    }
  }

  for (int t = tbeg; t < tend; ++t){
    const int rb   = t * RPB;
    const int rows = (n - rb < RPB) ? (n - rb) : RPB;

    // ---- prefetch next tile's inputs (in flight through compute+store) ----
    if (t + 1 < tend){
      const int r1 = (t+1) * RPB + row;
      if (r1 < n){
        const float* xr = x + (size_t)r1 * IN_DIM;
        nin[0] = xr[i];
        if (cls <= 1){
          #pragma unroll
          for (int k = 0; k < 3; ++k) nin[1+k] = xr[64 + i*3 + k];
        }
        if (cls == 0){
          #pragma unroll
          for (int k = 0; k < 5; ++k) nin[4+k] = xr[208 + i*5 + k];
        }
      }
    }

    // ---- compute current tile into LDS ----
    if (cls == 0){
      if (row < rows){
        const float s = cin[0];
        const float* p = &cin[1];
        const float* d = &cin[4];
        float* orow = sout + row * OUT_PAD;

        float o0 = 0.f;
        float o1[3] = {0.f,0.f,0.f};
        float o2[5] = {0.f,0.f,0.f,0.f,0.f};
        float o3[7] = {0.f,0.f,0.f,0.f,0.f,0.f,0.f};

        tp_path<0,0,0>(&s,&s, cf[ 0], &o0);
        tp_path<0,1,1>(&s, p, cf[ 1],  o1);
        tp_path<0,2,2>(&s, d, cf[ 2],  o2);
        tp_path<1,0,1>( p,&s, cf[ 3],  o1);
        tp_path<1,1,0>( p, p, cf[ 4], &o0);
        tp_path<1,1,1>( p, p, cf[ 5],  o1);
        tp_path<1,1,2>( p, p, cf[ 6],  o2);
        tp_path<1,2,1>( p, d, cf[ 7],  o1);
        tp_path<1,2,2>( p, d, cf[ 8],  o2);
        tp_path<1,2,3>( p, d, cf[ 9],  o3);
        tp_path<2,0,2>( d,&s, cf[10],  o2);
        tp_path<2,1,1>( d, p, cf[11],  o1);
        tp_path<2,1,2>( d, p, cf[12],  o2);
        tp_path<2,1,3>( d, p, cf[13],  o3);
        tp_path<2,2,0>( d, d, cf[14], &o0);
        tp_path<2,2,1>( d, d, cf[15],  o1);
        tp_path<2,2,2>( d, d, cf[16],  o2);
        tp_path<2,2,3>( d, d, cf[17],  o3);

        o0 += cf[18] * s;
        #pragma unroll
        for (int k = 0; k < 3; ++k) o1[k] += cf[19] * p[k];
        #pragma unroll
        for (int k = 0; k < 5; ++k) o2[k] += cf[20] * d[k];

        orow[i] = o0;
        #pragma unroll
        for (int k = 0; k < 3; ++k) orow[ 64 + i*3 + k] = o1[k];
        #pragma unroll
        for (int k = 0; k < 5; ++k) orow[208 + i*5 + k] = o2[k];
        #pragma unroll
        for (int k = 0; k < 7; ++k) orow[448 + i*7 + k] = o3[k];
      }
    } else if (cls == 1){
      if (row < rows){
        const float s = cin[0];
        const float* p = &cin[1];
        float* orow = sout + row * OUT_PAD;

        float o0 = 0.f;
        float o1[3] = {0.f,0.f,0.f};
        float o2[5] = {0.f,0.f,0.f,0.f,0.f};

        tp_path<0,0,0>(&s,&s, cf[0], &o0);
        tp_path<0,1,1>(&s, p, cf[1],  o1);
        tp_path<1,0,1>( p,&s, cf[2],  o1);
        tp_path<1,1,0>( p, p, cf[3], &o0);
        tp_path<1,1,1>( p, p, cf[4],  o1);
        tp_path<1,1,2>( p, p, cf[5],  o2);

        o0 += cf[6] * s;
        #pragma unroll
        for (int k = 0; k < 3; ++k) o1[k] += cf[7] * p[k];

        orow[i] = o0;
        #pragma unroll
        for (int k = 0; k < 3; ++k) orow[ 64 + i*3 + k] = o1[k];
        #pragma unroll
        for (int k = 0; k < 5; ++k) orow[208 + i*5 + k] = o2[k];
      }
    } else {
      if (row < rows){
        const float s = cin[0];
        float o0 = 0.f;
        tp_path<0,0,0>(&s,&s, cf[0], &o0);
        o0 += cf[1] * s;
        sout[row * OUT_PAD + i] = o0;
      }
    }

    sync_lds();   // LDS writes visible; vmcnt (prefetch, prior stores) untouched

    // ---- coalesced store: rows x 672 floats contiguous; LDS stride 676 ----
    {
      float4* gout = (float4*)(out + (size_t)rb * OUT_DIM);
      const float4* so4 = (const float4*)sout;     // row stride = 169 float4
      const int nf4 = rows * (OUT_DIM / 4);        // 168 per row
      for (int q = tid; q < nf4; q += 256){
        const int r = q / 168;
        const int j = q - r * 168;
        gout[q] = so4[r * 169 + j];                // fire-and-forget stores
      }
    }

    sync_lds();   // all waves' ds_reads done -> safe to rewrite sout next iter

    // ---- rotate pipeline registers ----
    #pragma unroll
    for (int k = 0; k < 9; ++k) cin[k] = nin[k];
  }
}

extern "C" void kernel_launch(void* const* d_in, const int* in_sizes, int n_in,
                              void* d_out, int out_size, void* d_ws, size_t ws_size,
                              hipStream_t stream)
{
  const float* x    = (const float*)d_in[0];
  const float* keep = (const float*)d_in[1];
  const float* mix  = (const float*)d_in[2];
  float* out = (float*)d_out;
  const int n = in_sizes[0] / IN_DIM;             // 32768
  selfmix_kernel<<<NBLK, 256, 0, stream>>>(x, keep, mix, out, n);
}